// Round 3
// baseline (826.970 us; speedup 1.0000x reference)
//
#include <hip/hip_runtime.h>
#include <math.h>

#define BATCH 512
#define SEQL  100
#define DIM   128
#define NITEMS 100000
#define NEGV  -1000000000.0f

// ---- workspace layout (float offsets); ws is ~819MB so plenty of room ----
#define OFF_WPACK_F 0         // 294912 halves = 147456 floats (3 mats x 24nt x 4c x hi/lo x 1KB-frag)
#define OFF_WREADT  147456    // 49152 floats  (W_read^T, [j*128+i])
#define OFF_APACK_F 196608    // 131072 halves = 65536 floats (hread frags)
#define OFF_HBUF    262144    // 512x100x128 fp32 = 6553600 floats
#define OFF_EPACK_F 6815744   // 25608192 halves = 12804096 floats (emb frags)
#define OFF_INFO_I  19619840  // int offset: 512x4: ec, li, flag, n_nodes

typedef __attribute__((ext_vector_type(8))) short bf16x8;
typedef __attribute__((ext_vector_type(4))) short s16x4;
typedef __attribute__((ext_vector_type(4))) float f32x4;

__device__ __forceinline__ unsigned short bf16_rne(float x) {
  unsigned int u = __float_as_uint(x);
  unsigned int r = u + 0x7FFFu + ((u >> 16) & 1u);
  return (unsigned short)(r >> 16);
}
__device__ __forceinline__ float bf16_to_f(unsigned short h) {
  return __uint_as_float(((unsigned int)h) << 16);
}

// ------------------------------------------------------------------
// K0 k_pack: all input-only packing in ONE launch.
//  - blocks [0, 6252): epack = emb as bf16 hi/lo A-frags (zero-pad to 100032 rows)
//  - blocks [6252, 6828): wpack = {Wc1=w_ih@W_in, Wc2=w_ih@W_out, w_hh} bf16 hi/lo B-frags
//  - blocks [6828, 7020): W_read^T
// frag rule: lane(quad,n) holds W[tile*16+n][chunk*32+quad*8+j], j=0..7
__global__ __launch_bounds__(256) void k_pack(
    const float* __restrict__ emb, const float* __restrict__ w_ih,
    const float* __restrict__ w_hh, const float* __restrict__ W_in,
    const float* __restrict__ W_out, const float* __restrict__ W_read,
    float* __restrict__ WreadT, unsigned short* __restrict__ wpack,
    unsigned short* __restrict__ epack) {
  int bid = blockIdx.x, tid = threadIdx.x;
  if (bid < 6252) {
    int idx = bid * 256 + tid;
    int lane = idx & 63;
    int kc = (idx >> 6) & 3;
    int it = idx >> 8;
    int quad = lane >> 4, rr = lane & 15;
    int row = it * 16 + rr;
    int kbase = kc * 32 + quad * 8;
    float4 v0 = {0.f, 0.f, 0.f, 0.f}, v1 = {0.f, 0.f, 0.f, 0.f};
    if (row < NITEMS) {
      const float4* p = (const float4*)(emb + (size_t)row * 128 + kbase);
      v0 = p[0]; v1 = p[1];
    }
    float vs[8] = {v0.x, v0.y, v0.z, v0.w, v1.x, v1.y, v1.z, v1.w};
    bf16x8 hi, lo;
    #pragma unroll
    for (int j = 0; j < 8; ++j) {
      unsigned short h = bf16_rne(vs[j]);
      hi[j] = (short)h;
      lo[j] = (short)bf16_rne(vs[j] - bf16_to_f(h));
    }
    size_t base = ((size_t)(it * 4 + kc) * 2) * 512 + (size_t)lane * 8;
    *(bf16x8*)&epack[base] = hi;
    *(bf16x8*)&epack[base + 512] = lo;
  } else if (bid < 6828) {
    int idx = (bid - 6252) * 256 + tid;          // < 147456
    int mat = idx / 49152, rem = idx % 49152;
    int n = rem >> 7, k = rem & 127;
    float v;
    if (mat == 2) {
      v = w_hh[rem];
    } else {
      const float* Wx = mat ? W_out : W_in;      // (128,128) row-major
      const float* wr = w_ih + n * 128;          // (384,128) row-major
      float s = 0.f;
      for (int m = 0; m < 128; ++m) s = fmaf(wr[m], Wx[m * 128 + k], s);
      v = s;
    }
    unsigned short hi = bf16_rne(v);
    unsigned short lo = bf16_rne(v - bf16_to_f(hi));
    int nt = n >> 4, nn2 = n & 15, c = k >> 5, quad = (k >> 3) & 3, j = k & 7;
    int lane = quad * 16 + nn2;
    size_t base = ((size_t)((mat * 24 + nt) * 4 + c)) * 1024 + (size_t)lane * 8 + j;
    wpack[base] = hi;
    wpack[base + 512] = lo;
  } else {
    int idx = (bid - 6828) * 256 + tid;          // < 49152
    int i = idx / 384, jj = idx % 384;           // W_read (128,384) row-major
    WreadT[jj * 128 + i] = W_read[idx];
  }
}

// ------------------------------------------------------------------
// K1 k_fused: per-sample megakernel.  grid=512, block=512 (8 waves), 1 block/CU.
// Phases: build(dedup/edges/deg) -> gather H0 (bf16 hi/lo in LDS) ->
// G[dst]+=H0[src] (fp32 LDS atomics) -> Gd=G/deg split in place ->
// GRU via MFMA: gi = H0@Wc1^T + Gd@Wc2^T, gh = H0@w_hh^T (3-term split each),
// weights double-buffer staged to LDS per (t,c) step -> H to global Hbuf.
__global__ __launch_bounds__(512) void k_fused(
    const int* __restrict__ x, const float* __restrict__ emb,
    const unsigned short* __restrict__ wpack,
    const float* __restrict__ b_ih, const float* __restrict__ b_hh,
    int* __restrict__ info, float* __restrict__ Hbuf) {
  __shared__ unsigned short H0s[2 * 112 * 136];  // hi | lo  (60928 B)
  __shared__ float Gmem[15232];                  // fp32 acc (pitch 132) -> bf16 split (pitch 136)
  __shared__ unsigned short Bst[2 * 9216];       // weight stage, 2 x 9 chunks x 1KB  (36864 B)
  __shared__ int sseq[SEQL];
  __shared__ unsigned char sisf[SEQL];
  __shared__ int srank[SEQL];
  __shared__ int scinv[SEQL];
  __shared__ int snodes[112];
  __shared__ float sdeg[112];
  __shared__ int s_nn, s_cnt;
  int b = blockIdx.x, tid = threadIdx.x;

  // ---- build ----
  if (tid < SEQL) sseq[tid] = x[b * SEQL + tid];
  if (tid < 112) { snodes[tid] = 0; sdeg[tid] = 0.f; }
  __syncthreads();
  int t = (tid < SEQL) ? sseq[tid] : 0;
  bool valid = (tid < SEQL) && (t != 0);
  int f = tid;
  if (valid) {
    for (int j = 0; j < tid; ++j) if (sseq[j] == t) { f = j; break; }
  }
  int isf = (valid && f == tid) ? 1 : 0;
  if (tid < SEQL) sisf[tid] = (unsigned char)isf;
  __syncthreads();
  int rank = 0, pos = 0;
  if (tid < SEQL) {
    for (int i = 0; i < tid; ++i) {
      rank += sisf[i];
      pos += (sseq[i] != 0) ? 1 : 0;
    }
    srank[tid] = rank;
    if (tid == SEQL - 1) { s_nn = rank + isf; s_cnt = pos + (valid ? 1 : 0); }
  }
  __syncthreads();
  if (valid) scinv[pos] = srank[f];
  if (isf) snodes[rank] = t;
  __syncthreads();
  int nn = s_nn, cnt = s_cnt;
  int ec = (cnt >= 2) ? cnt - 1 : 0;
  if (tid < ec) atomicAdd(&sdeg[scinv[tid + 1]], 1.f);
  if (tid == 0) {
    info[b * 4 + 0] = ec;
    info[b * 4 + 1] = (cnt >= 1) ? scinv[cnt - 1] : 0;
    info[b * 4 + 2] = (cnt >= 2) ? 1 : 0;
    info[b * 4 + 3] = nn;
  }
  // ---- gather H0 (split bf16) + zero G ----
  const float4* emb4 = (const float4*)emb;
  for (int e = tid; e < 112 * 32; e += 512) {
    int r = e >> 5, c4 = e & 31;
    float4 v = emb4[(size_t)snodes[r] * 32 + c4];   // snodes ready (barrier above)
    float vs[4] = {v.x, v.y, v.z, v.w};
    s16x4 hv, lv;
    #pragma unroll
    for (int q = 0; q < 4; ++q) {
      unsigned short h = bf16_rne(vs[q]);
      hv[q] = (short)h;
      lv[q] = (short)bf16_rne(vs[q] - bf16_to_f(h));
    }
    *(s16x4*)&H0s[r * 136 + c4 * 4] = hv;
    *(s16x4*)&H0s[112 * 136 + r * 136 + c4 * 4] = lv;
  }
  float4* G4 = (float4*)Gmem;
  for (int e = tid; e < 112 * 33; e += 512) G4[e] = (float4){0.f, 0.f, 0.f, 0.f};
  __syncthreads();
  // ---- G[dst] += H0[src] per edge ----
  for (int idx = tid; idx < ec * 128; idx += 512) {
    int e = idx >> 7, k = idx & 127;
    int src = scinv[e], dst = scinv[e + 1];
    float v = bf16_to_f(H0s[src * 136 + k]) + bf16_to_f(H0s[112 * 136 + src * 136 + k]);
    atomicAdd(&Gmem[dst * 132 + k], v);
  }
  __syncthreads();
  // ---- Gd = G/deg, split bf16 in place (reg-staged across barrier) ----
  float sv[28];
  #pragma unroll
  for (int u = 0; u < 28; ++u) {
    int e = tid + u * 512;                      // 112*128 = 28*512 exact
    int r = e >> 7, k = e & 127;
    sv[u] = Gmem[r * 132 + k] * (1.f / fmaxf(sdeg[r], 1.f));
  }
  __syncthreads();
  unsigned short* GdU = (unsigned short*)Gmem;
  #pragma unroll
  for (int u = 0; u < 28; ++u) {
    int e = tid + u * 512;
    int r = e >> 7, k = e & 127;
    unsigned short hi = bf16_rne(sv[u]);
    GdU[r * 136 + k] = hi;
    GdU[112 * 136 + r * 136 + k] = bf16_rne(sv[u] - bf16_to_f(hi));
  }
  __syncthreads();

  // ---- GRU ----
  int w = tid >> 6, lane = tid & 63;
  int quad = lane >> 4, nIdx = lane & 15;
  const uint4* wp4 = (const uint4*)wpack;
  uint4* bst4 = (uint4*)Bst;

  // hoist A-frags (waves 0-6, tile = w covers rows w*16 .. w*16+15)
  bf16x8 a0h[4], a0l[4], a1h[4], a1l[4];
  if (w < 7) {
    #pragma unroll
    for (int c = 0; c < 4; ++c) {
      int aoff = (w * 16 + nIdx) * 136 + c * 32 + quad * 8;
      a0h[c] = *(const bf16x8*)&H0s[aoff];
      a0l[c] = *(const bf16x8*)&H0s[112 * 136 + aoff];
      a1h[c] = *(const bf16x8*)&GdU[aoff];
      a1l[c] = *(const bf16x8*)&GdU[112 * 136 + aoff];
    }
  }
  // stage step 0 (tt=0,c=0) into buf 0
  #define STAGE(S, BS)                                                         \
    {                                                                          \
      int tts = (S) >> 2, cs = (S) & 3;                                        \
      for (int u = tid; u < 1152; u += 512) {                                  \
        int ch = u >> 7, off = u & 127;                                        \
        int g = ch / 3, mat = ch - 3 * g;                                      \
        bst4[(BS) * 1152 + ch * 128 + off] =                                   \
            wp4[((mat * 24 + g * 8 + tts) * 4 + cs) * 128 + off];              \
      }                                                                        \
    }
  STAGE(0, 0)
  __syncthreads();

  f32x4 acc[3][2];
  for (int s = 0; s < 32; ++s) {
    int bs = s & 1;
    if (s + 1 < 32) STAGE(s + 1, bs ^ 1)
    int tt = s >> 2, c = s & 3;
    if (w < 7) {
      if (c == 0) {
        #pragma unroll
        for (int g = 0; g < 3; ++g)
          #pragma unroll
          for (int m = 0; m < 2; ++m) acc[g][m] = (f32x4){0.f, 0.f, 0.f, 0.f};
      }
      bf16x8 Bh[3][3], Bl[3][3];
      #pragma unroll
      for (int g = 0; g < 3; ++g)
        #pragma unroll
        for (int mat = 0; mat < 3; ++mat) {
          int boff = bs * 9216 + (g * 3 + mat) * 1024 + lane * 8;
          Bh[g][mat] = *(const bf16x8*)&Bst[boff];
          Bl[g][mat] = *(const bf16x8*)&Bst[boff + 512];
        }
      #pragma unroll
      for (int g = 0; g < 3; ++g) {
        acc[g][0] = __builtin_amdgcn_mfma_f32_16x16x32_bf16(a0h[c], Bh[g][0], acc[g][0], 0, 0, 0);
        acc[g][1] = __builtin_amdgcn_mfma_f32_16x16x32_bf16(a0h[c], Bh[g][2], acc[g][1], 0, 0, 0);
      }
      #pragma unroll
      for (int g = 0; g < 3; ++g) {
        acc[g][0] = __builtin_amdgcn_mfma_f32_16x16x32_bf16(a1h[c], Bh[g][1], acc[g][0], 0, 0, 0);
        acc[g][1] = __builtin_amdgcn_mfma_f32_16x16x32_bf16(a0l[c], Bh[g][2], acc[g][1], 0, 0, 0);
      }
      #pragma unroll
      for (int g = 0; g < 3; ++g) {
        acc[g][0] = __builtin_amdgcn_mfma_f32_16x16x32_bf16(a0l[c], Bh[g][0], acc[g][0], 0, 0, 0);
        acc[g][1] = __builtin_amdgcn_mfma_f32_16x16x32_bf16(a0h[c], Bl[g][2], acc[g][1], 0, 0, 0);
      }
      #pragma unroll
      for (int g = 0; g < 3; ++g) {
        acc[g][0] = __builtin_amdgcn_mfma_f32_16x16x32_bf16(a1l[c], Bh[g][1], acc[g][0], 0, 0, 0);
        acc[g][0] = __builtin_amdgcn_mfma_f32_16x16x32_bf16(a0h[c], Bl[g][0], acc[g][0], 0, 0, 0);
        acc[g][0] = __builtin_amdgcn_mfma_f32_16x16x32_bf16(a1h[c], Bl[g][1], acc[g][0], 0, 0, 0);
      }
      if (c == 3) {
        int j = tt * 16 + nIdx;
        float biR = b_ih[j],       bhR = b_hh[j];
        float biZ = b_ih[128 + j], bhZ = b_hh[128 + j];
        float biN = b_ih[256 + j], bhN = b_hh[256 + j];
        #pragma unroll
        for (int i = 0; i < 4; ++i) {
          int row = w * 16 + quad * 4 + i;
          if (row < SEQL) {
            float gr = acc[0][0][i] + biR + acc[0][1][i] + bhR;
            float gz = acc[1][0][i] + biZ + acc[1][1][i] + bhZ;
            float r = 1.f / (1.f + expf(-gr));
            float z = 1.f / (1.f + expf(-gz));
            float nct = tanhf(acc[2][0][i] + biN + r * (acc[2][1][i] + bhN));
            float h0 = bf16_to_f(H0s[row * 136 + j]) + bf16_to_f(H0s[112 * 136 + row * 136 + j]);
            float h = (1.f - z) * nct + z * h0;
            if (row >= nn) h = 0.f;
            Hbuf[((size_t)b * SEQL + row) * 128 + j] = h;
          }
        }
      }
    }
    __syncthreads();
  }
  #undef STAGE
}

// ------------------------------------------------------------------
// K2 k_attn: attention + h_read + apack write.  grid=512, block=128
#define HLS 129
__global__ void k_attn(const float* __restrict__ Hbuf, const float* __restrict__ WrT,
                       const float* __restrict__ b_read, const int* __restrict__ info,
                       unsigned short* __restrict__ apack) {
  int b = blockIdx.x, tid = threadIdx.x;
  __shared__ float Hl[SEQL * HLS];
  __shared__ float sc[128];
  __shared__ float hl[128];
  __shared__ float att[SEQL];
  __shared__ float loc[128];
  __shared__ float redm[2], reds[2];
  int nn = info[b * 4 + 3], li = info[b * 4 + 1];
  for (int e = tid; e < SEQL * 128; e += 128) {
    int r = e >> 7, k = e & 127;
    Hl[r * HLS + k] = Hbuf[((size_t)(b * SEQL + r)) * DIM + k];
  }
  __syncthreads();
  hl[tid] = Hl[li * HLS + tid];
  __syncthreads();
  float scr = NEGV;
  if (tid < nn) {
    float s = 0.f;
    for (int k = 0; k < 128; ++k) s += Hl[tid * HLS + k] * hl[k];
    scr = s;
  }
  sc[tid] = scr;
  __syncthreads();
  float m = sc[tid];
  #pragma unroll
  for (int o = 32; o >= 1; o >>= 1) m = fmaxf(m, __shfl_xor(m, o, 64));
  if ((tid & 63) == 0) redm[tid >> 6] = m;
  __syncthreads();
  m = fmaxf(redm[0], redm[1]);
  float e = (tid < SEQL) ? expf(sc[tid] - m) : 0.f;
  float s = e;
  #pragma unroll
  for (int o = 32; o >= 1; o >>= 1) s += __shfl_xor(s, o, 64);
  if ((tid & 63) == 0) reds[tid >> 6] = s;
  __syncthreads();
  float inv = 1.f / (reds[0] + reds[1]);
  if (tid < SEQL) att[tid] = e * inv;
  __syncthreads();
  float lv = 0.f;
  for (int n = 0; n < SEQL; ++n) lv = fmaf(att[n], Hl[n * HLS + tid], lv);
  loc[tid] = lv;
  __syncthreads();
  float acc = b_read[tid];
  for (int j = 0; j < 128; ++j) acc = fmaf(WrT[j * 128 + tid], hl[j], acc);
  for (int j = 0; j < 128; ++j) acc = fmaf(WrT[(128 + j) * 128 + tid], loc[j], acc);
  float hr = tanhf(acc);
  // ---- packA fold: write hread frag halves (B-role for k_out) ----
  int mt = b >> 4, rr = b & 15;
  int kc = tid >> 5, q2 = (tid >> 3) & 3, j2 = tid & 7;
  unsigned short hi = bf16_rne(hr);
  unsigned short lo = bf16_rne(hr - bf16_to_f(hi));
  size_t base = ((size_t)(mt * 4 + kc) * 2) * 512 + (size_t)(q2 * 16 + rr) * 8 + j2;
  apack[base] = hi;
  apack[base + 512] = lo;
}

// ------------------------------------------------------------------
// K3 k_out: out = h_read @ emb^T, operand-swapped (C[item][b]) -> float4 stores.
// Pure-register: no LDS, no barriers.  grid (4, 1563), block 256 = 4 waves.
__global__ __launch_bounds__(256) void k_out(
    const unsigned short* __restrict__ epack, const unsigned short* __restrict__ apack,
    const int* __restrict__ info, float* __restrict__ out) {
  int tid = threadIdx.x;
  int wave = tid >> 6, lane = tid & 63;
  int quad = lane >> 4, nIdx = lane & 15;
  int b0   = blockIdx.x * 128;
  int itt0 = blockIdx.y * 4;
  int btg0 = blockIdx.x * 8 + wave * 2;

  bf16x8 bh[2][4], bl[2][4];
  #pragma unroll
  for (int m2 = 0; m2 < 2; ++m2)
    #pragma unroll
    for (int kc = 0; kc < 4; ++kc) {
      size_t base = ((size_t)((btg0 + m2) * 4 + kc) * 2) * 512 + (size_t)lane * 8;
      bh[m2][kc] = *(const bf16x8*)&apack[base];
      bl[m2][kc] = *(const bf16x8*)&apack[base + 512];
    }

  f32x4 acc[4][2];
  #pragma unroll
  for (int it = 0; it < 4; ++it)
    #pragma unroll
    for (int m2 = 0; m2 < 2; ++m2) acc[it][m2] = (f32x4){0.f, 0.f, 0.f, 0.f};

  #pragma unroll
  for (int it = 0; it < 4; ++it) {
    #pragma unroll
    for (int kc = 0; kc < 4; ++kc) {
      size_t abase = ((size_t)((itt0 + it) * 4 + kc) * 2) * 512 + (size_t)lane * 8;
      bf16x8 Ah = *(const bf16x8*)&epack[abase];
      bf16x8 Al = *(const bf16x8*)&epack[abase + 512];
      acc[it][0] = __builtin_amdgcn_mfma_f32_16x16x32_bf16(Ah, bh[0][kc], acc[it][0], 0, 0, 0);
      acc[it][1] = __builtin_amdgcn_mfma_f32_16x16x32_bf16(Ah, bh[1][kc], acc[it][1], 0, 0, 0);
      acc[it][0] = __builtin_amdgcn_mfma_f32_16x16x32_bf16(Al, bh[0][kc], acc[it][0], 0, 0, 0);
      acc[it][1] = __builtin_amdgcn_mfma_f32_16x16x32_bf16(Al, bh[1][kc], acc[it][1], 0, 0, 0);
      acc[it][0] = __builtin_amdgcn_mfma_f32_16x16x32_bf16(Ah, bl[0][kc], acc[it][0], 0, 0, 0);
      acc[it][1] = __builtin_amdgcn_mfma_f32_16x16x32_bf16(Ah, bl[1][kc], acc[it][1], 0, 0, 0);
    }
  }

  #pragma unroll
  for (int m2 = 0; m2 < 2; ++m2) {
    int b = b0 + (wave * 2 + m2) * 16 + nIdx;
    int flag = info[b * 4 + 2];
    #pragma unroll
    for (int it = 0; it < 4; ++it) {
      int ib = (itt0 + it) * 16 + quad * 4;
      if (ib < NITEMS) {
        float4 v;
        if (flag) {
          v.x = acc[it][m2][0]; v.y = acc[it][m2][1];
          v.z = acc[it][m2][2]; v.w = acc[it][m2][3];
        } else {
          v.x = (ib == 0) ? 0.f : NEGV; v.y = NEGV; v.z = NEGV; v.w = NEGV;
        }
        *(float4*)&out[(size_t)b * NITEMS + ib] = v;
      }
    }
  }
}

// ------------------------------------------------------------------
extern "C" void kernel_launch(void* const* d_in, const int* in_sizes, int n_in,
                              void* d_out, int out_size, void* d_ws, size_t ws_size,
                              hipStream_t stream) {
  const int*   x      = (const int*)d_in[0];
  const float* emb    = (const float*)d_in[2];
  const float* W_in   = (const float*)d_in[3];
  const float* W_out  = (const float*)d_in[4];
  const float* w_ih   = (const float*)d_in[5];
  const float* w_hh   = (const float*)d_in[6];
  const float* b_ih   = (const float*)d_in[7];
  const float* b_hh   = (const float*)d_in[8];
  const float* W_read = (const float*)d_in[9];
  const float* b_read = (const float*)d_in[10];
  float* ws  = (float*)d_ws;
  int*   wsi = (int*)d_ws;
  unsigned short* wpack = (unsigned short*)(ws + OFF_WPACK_F);
  float*          WreadT = ws + OFF_WREADT;
  unsigned short* apack = (unsigned short*)(ws + OFF_APACK_F);
  float*          Hbuf  = ws + OFF_HBUF;
  unsigned short* epack = (unsigned short*)(ws + OFF_EPACK_F);
  int*            info  = wsi + OFF_INFO_I;
  float* out = (float*)d_out;

  k_pack<<<7020, 256, 0, stream>>>(emb, w_ih, w_hh, W_in, W_out, W_read,
                                   WreadT, wpack, epack);
  k_fused<<<BATCH, 512, 0, stream>>>(x, emb, wpack, b_ih, b_hh, info, Hbuf);
  k_attn<<<BATCH, 128, 0, stream>>>(Hbuf, WreadT, b_read, info, apack);
  k_out<<<dim3(4, 1563), 256, 0, stream>>>(epack, apack, info, out);
}

// Round 4
// 524.147 us; speedup vs baseline: 1.5777x; 1.5777x over previous
//
#include <hip/hip_runtime.h>
#include <math.h>

#define BATCH 512
#define SEQL  100
#define DIM   128
#define NITEMS 100000
#define NEGV  -1000000000.0f

// ---- workspace layout (float offsets) ----
#define OFF_WPACK_F 0         // 294912 halves = 147456 floats ({Wc1,Wc2,w_hh} frags)
#define OFF_WREADT  147456    // 49152 floats  (W_read^T, [j*128+i])
#define OFF_APACK_F 196608    // 131072 halves = 65536 floats (hread frags)
#define OFF_HBUF    262144    // 512x100x128 fp32
#define OFF_GD      6815744   // 512x100x128 fp32 (G/deg)
#define OFF_EPACK_F 13369344  // 25608192 halves = 12804096 floats (emb frags)
// ---- int offsets ----
#define OFF_NODES_I 26173440  // 512x100
#define OFF_SRC_I   26224640  // 512x99
#define OFF_DST_I   26275328  // 512x99
#define OFF_INFO_I  26326016  // 512x4: ec, li, flag(cnt>=2), n_nodes

typedef __attribute__((ext_vector_type(8))) short bf16x8;
typedef __attribute__((ext_vector_type(4))) short s16x4;
typedef __attribute__((ext_vector_type(4))) float f32x4;

__device__ __forceinline__ unsigned short bf16_rne(float x) {
  unsigned int u = __float_as_uint(x);
  unsigned int r = u + 0x7FFFu + ((u >> 16) & 1u);
  return (unsigned short)(r >> 16);
}
__device__ __forceinline__ float bf16_to_f(unsigned short h) {
  return __uint_as_float(((unsigned int)h) << 16);
}

// ------------------------------------------------------------------
// K0 k_pack (verified r3): epack emb frags | wpack {Wc1=w_ih@W_in, Wc2=w_ih@W_out,
// w_hh} frags | W_read^T.  frag rule: lane(quad,n) holds W[tile*16+n][chunk*32+quad*8+j]
__global__ __launch_bounds__(256) void k_pack(
    const float* __restrict__ emb, const float* __restrict__ w_ih,
    const float* __restrict__ w_hh, const float* __restrict__ W_in,
    const float* __restrict__ W_out, const float* __restrict__ W_read,
    float* __restrict__ WreadT, unsigned short* __restrict__ wpack,
    unsigned short* __restrict__ epack) {
  int bid = blockIdx.x, tid = threadIdx.x;
  if (bid < 6252) {
    int idx = bid * 256 + tid;
    int lane = idx & 63;
    int kc = (idx >> 6) & 3;
    int it = idx >> 8;
    int quad = lane >> 4, rr = lane & 15;
    int row = it * 16 + rr;
    int kbase = kc * 32 + quad * 8;
    float4 v0 = {0.f, 0.f, 0.f, 0.f}, v1 = {0.f, 0.f, 0.f, 0.f};
    if (row < NITEMS) {
      const float4* p = (const float4*)(emb + (size_t)row * 128 + kbase);
      v0 = p[0]; v1 = p[1];
    }
    float vs[8] = {v0.x, v0.y, v0.z, v0.w, v1.x, v1.y, v1.z, v1.w};
    bf16x8 hi, lo;
    #pragma unroll
    for (int j = 0; j < 8; ++j) {
      unsigned short h = bf16_rne(vs[j]);
      hi[j] = (short)h;
      lo[j] = (short)bf16_rne(vs[j] - bf16_to_f(h));
    }
    size_t base = ((size_t)(it * 4 + kc) * 2) * 512 + (size_t)lane * 8;
    *(bf16x8*)&epack[base] = hi;
    *(bf16x8*)&epack[base + 512] = lo;
  } else if (bid < 6828) {
    int idx = (bid - 6252) * 256 + tid;          // < 147456
    int mat = idx / 49152, rem = idx % 49152;
    int n = rem >> 7, k = rem & 127;
    float v;
    if (mat == 2) {
      v = w_hh[rem];
    } else {
      const float* Wx = mat ? W_out : W_in;      // (128,128) row-major
      const float* wr = w_ih + n * 128;          // (384,128) row-major
      float s = 0.f;
      for (int m = 0; m < 128; ++m) s = fmaf(wr[m], Wx[m * 128 + k], s);
      v = s;
    }
    unsigned short hi = bf16_rne(v);
    unsigned short lo = bf16_rne(v - bf16_to_f(hi));
    int nt = n >> 4, nn2 = n & 15, c = k >> 5, quad = (k >> 3) & 3, j = k & 7;
    int lane = quad * 16 + nn2;
    size_t base = ((size_t)((mat * 24 + nt) * 4 + c)) * 1024 + (size_t)lane * 8 + j;
    wpack[base] = hi;
    wpack[base + 512] = lo;
  } else {
    int idx = (bid - 6828) * 256 + tid;          // < 49152
    int i = idx / 384, jj = idx % 384;           // W_read (128,384) row-major
    WreadT[jj * 128 + i] = W_read[idx];
  }
}

// ------------------------------------------------------------------
// K1 k_build: parallel dedup/edges (logic verified in r3).  grid=512, block=128.
__global__ void k_build(const int* __restrict__ x, int* __restrict__ nodes,
                        int* __restrict__ esrc, int* __restrict__ edst,
                        int* __restrict__ info) {
  int b = blockIdx.x, tid = threadIdx.x;
  __shared__ int sseq[SEQL];
  __shared__ unsigned char sisf[SEQL];
  __shared__ int srank[SEQL];
  __shared__ int scinv[SEQL];
  __shared__ int snodes[SEQL];
  __shared__ int s_nn, s_cnt;
  if (tid < SEQL) { sseq[tid] = x[b * SEQL + tid]; snodes[tid] = 0; }
  __syncthreads();
  int t = (tid < SEQL) ? sseq[tid] : 0;
  bool valid = (tid < SEQL) && (t != 0);
  int f = tid;
  if (valid) {
    for (int j = 0; j < tid; ++j) if (sseq[j] == t) { f = j; break; }
  }
  int isf = (valid && f == tid) ? 1 : 0;
  if (tid < SEQL) sisf[tid] = (unsigned char)isf;
  __syncthreads();
  int rank = 0, pos = 0;
  if (tid < SEQL) {
    for (int i = 0; i < tid; ++i) {
      rank += sisf[i];
      pos += (sseq[i] != 0) ? 1 : 0;
    }
    srank[tid] = rank;
    if (tid == SEQL - 1) { s_nn = rank + isf; s_cnt = pos + (valid ? 1 : 0); }
  }
  __syncthreads();
  if (valid) scinv[pos] = srank[f];
  if (isf) snodes[rank] = t;
  __syncthreads();
  int nn = s_nn, cnt = s_cnt;
  int ec = (cnt >= 2) ? cnt - 1 : 0;
  if (tid < ec) {
    esrc[b * 99 + tid] = scinv[tid];
    edst[b * 99 + tid] = scinv[tid + 1];
  }
  if (tid == 0) {
    info[b * 4 + 0] = ec;
    info[b * 4 + 1] = (cnt >= 1) ? scinv[cnt - 1] : 0;
    info[b * 4 + 2] = (cnt >= 2) ? 1 : 0;
    info[b * 4 + 3] = nn;
  }
  if (tid < SEQL) nodes[b * SEQL + tid] = snodes[tid];
}

// ------------------------------------------------------------------
// K2 k_agg: Gd[b][n] = (sum_{e:dst=n} emb[nodes[src_e]]) / max(deg,1).
// grid=512, block=256 (2 edges in flight), LDS fp32 atomics.
__global__ __launch_bounds__(256) void k_agg(
    const float* __restrict__ emb, const int* __restrict__ nodes,
    const int* __restrict__ esrc, const int* __restrict__ edst,
    const int* __restrict__ info, float* __restrict__ Gd) {
  __shared__ float agg[SEQL * DIM];
  __shared__ float sdeg[SEQL];
  int b = blockIdx.x, tid = threadIdx.x;
  float4* a4 = (float4*)agg;
  for (int e = tid; e < SEQL * 32; e += 256) a4[e] = (float4){0.f, 0.f, 0.f, 0.f};
  if (tid < SEQL) sdeg[tid] = 0.f;
  __syncthreads();
  int ec = info[b * 4 + 0];
  if (tid < ec) atomicAdd(&sdeg[edst[b * 99 + tid]], 1.f);
  for (int idx = tid; idx < ec * DIM; idx += 256) {
    int e = idx >> 7, k = idx & 127;
    int tok = nodes[b * SEQL + esrc[b * 99 + e]];
    atomicAdd(&agg[edst[b * 99 + e] * DIM + k], emb[(size_t)tok * DIM + k]);
  }
  __syncthreads();
  for (int idx = tid; idx < SEQL * DIM; idx += 256) {
    int n = idx >> 7;
    Gd[((size_t)b * SEQL) * DIM + idx] = agg[idx] * (1.f / fmaxf(sdeg[n], 1.f));
  }
}

// ------------------------------------------------------------------
// K3 k_gru v4: gi = H0@Wc1^T + Gd@Wc2^T, gh = H0@w_hh^T (3-term split each).
// grid=800 (64 rows/block), block=128 (2 waves), each wave 2 m-tiles.
// B-frags from L2 per wave, amortized over 32 rows/wave.
#define GPAD 136
__global__ __launch_bounds__(128) void k_gru(
    const float* __restrict__ emb, const int* __restrict__ nodes,
    const unsigned short* __restrict__ wpack, const float* __restrict__ Gd,
    const float* __restrict__ b_ih, const float* __restrict__ b_hh,
    const int* __restrict__ info, float* __restrict__ Hbuf) {
  __shared__ unsigned short Xhi[64 * GPAD];   // Gd split
  __shared__ unsigned short Xlo[64 * GPAD];
  __shared__ unsigned short Hhi[64 * GPAD];   // H0 split
  __shared__ unsigned short Hlo[64 * GPAD];
  int tid = threadIdx.x;
  int rowbase = blockIdx.x * 64;
  const float4* emb4 = (const float4*)emb;
  const float4* gd4 = (const float4*)Gd;
  for (int e = tid; e < 64 * 32; e += 128) {
    int r = e >> 5, c4 = e & 31;
    int row = rowbase + r;
    float4 xv = gd4[(size_t)row * 32 + c4];
    int tok = nodes[row];
    float4 hv = emb4[(size_t)tok * 32 + c4];
    int base = r * GPAD + c4 * 4;
    float xs[4] = {xv.x, xv.y, xv.z, xv.w};
    float hs[4] = {hv.x, hv.y, hv.z, hv.w};
    s16x4 xh, xl, hh, hl;
    #pragma unroll
    for (int q = 0; q < 4; ++q) {
      unsigned short h1 = bf16_rne(xs[q]);
      xh[q] = (short)h1; xl[q] = (short)bf16_rne(xs[q] - bf16_to_f(h1));
      unsigned short h2 = bf16_rne(hs[q]);
      hh[q] = (short)h2; hl[q] = (short)bf16_rne(hs[q] - bf16_to_f(h2));
    }
    *(s16x4*)&Xhi[base] = xh; *(s16x4*)&Xlo[base] = xl;
    *(s16x4*)&Hhi[base] = hh; *(s16x4*)&Hlo[base] = hl;
  }
  __syncthreads();
  int wave = tid >> 6, lane = tid & 63;
  int quad = lane >> 4, nIdx = lane & 15;
  int grows[2][4]; int zm[2][4];
  #pragma unroll
  for (int m = 0; m < 2; ++m)
    #pragma unroll
    for (int i = 0; i < 4; ++i) {
      int grow = rowbase + (wave * 2 + m) * 16 + quad * 4 + i;
      grows[m][i] = grow;
      int bs = grow / SEQL;
      int n = grow - bs * SEQL;
      zm[m][i] = (n < info[bs * 4 + 3]) ? 1 : 0;
    }

  for (int t = 0; t < 8; ++t) {
    f32x4 acc[2][3][2];                 // [mtile][gate][gi/gh]
    #pragma unroll
    for (int m = 0; m < 2; ++m)
      #pragma unroll
      for (int g = 0; g < 3; ++g)
        #pragma unroll
        for (int p = 0; p < 2; ++p) acc[m][g][p] = (f32x4){0.f, 0.f, 0.f, 0.f};

    #pragma unroll
    for (int c = 0; c < 4; ++c) {
      bf16x8 aX[2][2], aH[2][2];        // [mtile][hi/lo]
      #pragma unroll
      for (int m = 0; m < 2; ++m) {
        int off = ((wave * 2 + m) * 16 + nIdx) * GPAD + c * 32 + quad * 8;
        aX[m][0] = *(const bf16x8*)&Xhi[off];
        aX[m][1] = *(const bf16x8*)&Xlo[off];
        aH[m][0] = *(const bf16x8*)&Hhi[off];
        aH[m][1] = *(const bf16x8*)&Hlo[off];
      }
      #pragma unroll
      for (int g = 0; g < 3; ++g) {
        size_t base1 = ((size_t)((0 * 24 + g * 8 + t) * 4 + c)) * 1024 + (size_t)lane * 8;
        size_t base2 = ((size_t)((1 * 24 + g * 8 + t) * 4 + c)) * 1024 + (size_t)lane * 8;
        size_t base3 = ((size_t)((2 * 24 + g * 8 + t) * 4 + c)) * 1024 + (size_t)lane * 8;
        bf16x8 B1h = *(const bf16x8*)&wpack[base1];
        bf16x8 B1l = *(const bf16x8*)&wpack[base1 + 512];
        bf16x8 B2h = *(const bf16x8*)&wpack[base2];
        bf16x8 B2l = *(const bf16x8*)&wpack[base2 + 512];
        bf16x8 B3h = *(const bf16x8*)&wpack[base3];
        bf16x8 B3l = *(const bf16x8*)&wpack[base3 + 512];
        #pragma unroll
        for (int m = 0; m < 2; ++m) {
          // hi*hi
          acc[m][g][0] = __builtin_amdgcn_mfma_f32_16x16x32_bf16(aH[m][0], B1h, acc[m][g][0], 0, 0, 0);
          acc[m][g][0] = __builtin_amdgcn_mfma_f32_16x16x32_bf16(aX[m][0], B2h, acc[m][g][0], 0, 0, 0);
          acc[m][g][1] = __builtin_amdgcn_mfma_f32_16x16x32_bf16(aH[m][0], B3h, acc[m][g][1], 0, 0, 0);
          // lo*hi
          acc[m][g][0] = __builtin_amdgcn_mfma_f32_16x16x32_bf16(aH[m][1], B1h, acc[m][g][0], 0, 0, 0);
          acc[m][g][0] = __builtin_amdgcn_mfma_f32_16x16x32_bf16(aX[m][1], B2h, acc[m][g][0], 0, 0, 0);
          acc[m][g][1] = __builtin_amdgcn_mfma_f32_16x16x32_bf16(aH[m][1], B3h, acc[m][g][1], 0, 0, 0);
          // hi*lo
          acc[m][g][0] = __builtin_amdgcn_mfma_f32_16x16x32_bf16(aH[m][0], B1l, acc[m][g][0], 0, 0, 0);
          acc[m][g][0] = __builtin_amdgcn_mfma_f32_16x16x32_bf16(aX[m][0], B2l, acc[m][g][0], 0, 0, 0);
          acc[m][g][1] = __builtin_amdgcn_mfma_f32_16x16x32_bf16(aH[m][0], B3l, acc[m][g][1], 0, 0, 0);
        }
      }
    }
    int j = t * 16 + nIdx;
    float biR = b_ih[j],       bhR = b_hh[j];
    float biZ = b_ih[128 + j], bhZ = b_hh[128 + j];
    float biN = b_ih[256 + j], bhN = b_hh[256 + j];
    #pragma unroll
    for (int m = 0; m < 2; ++m)
      #pragma unroll
      for (int i = 0; i < 4; ++i) {
        float gr = acc[m][0][0][i] + biR + acc[m][0][1][i] + bhR;
        float gz = acc[m][1][0][i] + biZ + acc[m][1][1][i] + bhZ;
        float r = 1.f / (1.f + expf(-gr));
        float z = 1.f / (1.f + expf(-gz));
        float nct = tanhf(acc[m][2][0][i] + biN + r * (acc[m][2][1][i] + bhN));
        int lrow = (wave * 2 + m) * 16 + quad * 4 + i;
        float h0 = bf16_to_f(Hhi[lrow * GPAD + j]) + bf16_to_f(Hlo[lrow * GPAD + j]);
        float h = (1.f - z) * nct + z * h0;
        if (!zm[m][i]) h = 0.f;
        Hbuf[(size_t)grows[m][i] * 128 + j] = h;
      }
  }
}

// ------------------------------------------------------------------
// K4 k_attn (verified r3): attention + h_read + apack fold.  grid=512, block=128
#define HLS 129
__global__ void k_attn(const float* __restrict__ Hbuf, const float* __restrict__ WrT,
                       const float* __restrict__ b_read, const int* __restrict__ info,
                       unsigned short* __restrict__ apack) {
  int b = blockIdx.x, tid = threadIdx.x;
  __shared__ float Hl[SEQL * HLS];
  __shared__ float sc[128];
  __shared__ float hl[128];
  __shared__ float att[SEQL];
  __shared__ float loc[128];
  __shared__ float redm[2], reds[2];
  int nn = info[b * 4 + 3], li = info[b * 4 + 1];
  for (int e = tid; e < SEQL * 128; e += 128) {
    int r = e >> 7, k = e & 127;
    Hl[r * HLS + k] = Hbuf[((size_t)(b * SEQL + r)) * DIM + k];
  }
  __syncthreads();
  hl[tid] = Hl[li * HLS + tid];
  __syncthreads();
  float scr = NEGV;
  if (tid < nn) {
    float s = 0.f;
    for (int k = 0; k < 128; ++k) s += Hl[tid * HLS + k] * hl[k];
    scr = s;
  }
  sc[tid] = scr;
  __syncthreads();
  float m = sc[tid];
  #pragma unroll
  for (int o = 32; o >= 1; o >>= 1) m = fmaxf(m, __shfl_xor(m, o, 64));
  if ((tid & 63) == 0) redm[tid >> 6] = m;
  __syncthreads();
  m = fmaxf(redm[0], redm[1]);
  float e = (tid < SEQL) ? expf(sc[tid] - m) : 0.f;
  float s = e;
  #pragma unroll
  for (int o = 32; o >= 1; o >>= 1) s += __shfl_xor(s, o, 64);
  if ((tid & 63) == 0) reds[tid >> 6] = s;
  __syncthreads();
  float inv = 1.f / (reds[0] + reds[1]);
  if (tid < SEQL) att[tid] = e * inv;
  __syncthreads();
  float lv = 0.f;
  for (int n = 0; n < SEQL; ++n) lv = fmaf(att[n], Hl[n * HLS + tid], lv);
  loc[tid] = lv;
  __syncthreads();
  float acc = b_read[tid];
  for (int j = 0; j < 128; ++j) acc = fmaf(WrT[j * 128 + tid], hl[j], acc);
  for (int j = 0; j < 128; ++j) acc = fmaf(WrT[(128 + j) * 128 + tid], loc[j], acc);
  float hr = tanhf(acc);
  int mt = b >> 4, rr = b & 15;
  int kc = tid >> 5, q2 = (tid >> 3) & 3, j2 = tid & 7;
  unsigned short hi = bf16_rne(hr);
  unsigned short lo = bf16_rne(hr - bf16_to_f(hi));
  size_t base = ((size_t)(mt * 4 + kc) * 2) * 512 + (size_t)(q2 * 16 + rr) * 8 + j2;
  apack[base] = hi;
  apack[base + 512] = lo;
}

// ------------------------------------------------------------------
// K5 k_out (verified r1-3): out = h_read @ emb^T, operand-swapped (C[item][b]).
// Pure-register.  grid (4, 1563), block 256 = 4 waves.
__global__ __launch_bounds__(256) void k_out(
    const unsigned short* __restrict__ epack, const unsigned short* __restrict__ apack,
    const int* __restrict__ info, float* __restrict__ out) {
  int tid = threadIdx.x;
  int wave = tid >> 6, lane = tid & 63;
  int quad = lane >> 4, nIdx = lane & 15;
  int b0   = blockIdx.x * 128;
  int itt0 = blockIdx.y * 4;
  int btg0 = blockIdx.x * 8 + wave * 2;

  bf16x8 bh[2][4], bl[2][4];
  #pragma unroll
  for (int m2 = 0; m2 < 2; ++m2)
    #pragma unroll
    for (int kc = 0; kc < 4; ++kc) {
      size_t base = ((size_t)((btg0 + m2) * 4 + kc) * 2) * 512 + (size_t)lane * 8;
      bh[m2][kc] = *(const bf16x8*)&apack[base];
      bl[m2][kc] = *(const bf16x8*)&apack[base + 512];
    }

  f32x4 acc[4][2];
  #pragma unroll
  for (int it = 0; it < 4; ++it)
    #pragma unroll
    for (int m2 = 0; m2 < 2; ++m2) acc[it][m2] = (f32x4){0.f, 0.f, 0.f, 0.f};

  #pragma unroll
  for (int it = 0; it < 4; ++it) {
    #pragma unroll
    for (int kc = 0; kc < 4; ++kc) {
      size_t abase = ((size_t)((itt0 + it) * 4 + kc) * 2) * 512 + (size_t)lane * 8;
      bf16x8 Ah = *(const bf16x8*)&epack[abase];
      bf16x8 Al = *(const bf16x8*)&epack[abase + 512];
      acc[it][0] = __builtin_amdgcn_mfma_f32_16x16x32_bf16(Ah, bh[0][kc], acc[it][0], 0, 0, 0);
      acc[it][1] = __builtin_amdgcn_mfma_f32_16x16x32_bf16(Ah, bh[1][kc], acc[it][1], 0, 0, 0);
      acc[it][0] = __builtin_amdgcn_mfma_f32_16x16x32_bf16(Al, bh[0][kc], acc[it][0], 0, 0, 0);
      acc[it][1] = __builtin_amdgcn_mfma_f32_16x16x32_bf16(Al, bh[1][kc], acc[it][1], 0, 0, 0);
      acc[it][0] = __builtin_amdgcn_mfma_f32_16x16x32_bf16(Ah, bl[0][kc], acc[it][0], 0, 0, 0);
      acc[it][1] = __builtin_amdgcn_mfma_f32_16x16x32_bf16(Ah, bl[1][kc], acc[it][1], 0, 0, 0);
    }
  }

  #pragma unroll
  for (int m2 = 0; m2 < 2; ++m2) {
    int b = b0 + (wave * 2 + m2) * 16 + nIdx;
    int flag = info[b * 4 + 2];
    #pragma unroll
    for (int it = 0; it < 4; ++it) {
      int ib = (itt0 + it) * 16 + quad * 4;
      if (ib < NITEMS) {
        float4 v;
        if (flag) {
          v.x = acc[it][m2][0]; v.y = acc[it][m2][1];
          v.z = acc[it][m2][2]; v.w = acc[it][m2][3];
        } else {
          v.x = (ib == 0) ? 0.f : NEGV; v.y = NEGV; v.z = NEGV; v.w = NEGV;
        }
        *(float4*)&out[(size_t)b * NITEMS + ib] = v;
      }
    }
  }
}

// ------------------------------------------------------------------
extern "C" void kernel_launch(void* const* d_in, const int* in_sizes, int n_in,
                              void* d_out, int out_size, void* d_ws, size_t ws_size,
                              hipStream_t stream) {
  const int*   x      = (const int*)d_in[0];
  const float* emb    = (const float*)d_in[2];
  const float* W_in   = (const float*)d_in[3];
  const float* W_out  = (const float*)d_in[4];
  const float* w_ih   = (const float*)d_in[5];
  const float* w_hh   = (const float*)d_in[6];
  const float* b_ih   = (const float*)d_in[7];
  const float* b_hh   = (const float*)d_in[8];
  const float* W_read = (const float*)d_in[9];
  const float* b_read = (const float*)d_in[10];
  float* ws  = (float*)d_ws;
  int*   wsi = (int*)d_ws;
  unsigned short* wpack  = (unsigned short*)(ws + OFF_WPACK_F);
  float*          WreadT = ws + OFF_WREADT;
  unsigned short* apack  = (unsigned short*)(ws + OFF_APACK_F);
  float*          Hbuf   = ws + OFF_HBUF;
  float*          GdBuf  = ws + OFF_GD;
  unsigned short* epack  = (unsigned short*)(ws + OFF_EPACK_F);
  int*            nodes  = wsi + OFF_NODES_I;
  int*            esrc   = wsi + OFF_SRC_I;
  int*            edst   = wsi + OFF_DST_I;
  int*            info   = wsi + OFF_INFO_I;
  float* out = (float*)d_out;

  k_pack<<<7020, 256, 0, stream>>>(emb, w_ih, w_hh, W_in, W_out, W_read,
                                   WreadT, wpack, epack);
  k_build<<<BATCH, 128, 0, stream>>>(x, nodes, esrc, edst, info);
  k_agg<<<BATCH, 256, 0, stream>>>(emb, nodes, esrc, edst, info, GdBuf);
  k_gru<<<800, 128, 0, stream>>>(emb, nodes, wpack, GdBuf, b_ih, b_hh, info, Hbuf);
  k_attn<<<BATCH, 128, 0, stream>>>(Hbuf, WreadT, b_read, info, apack);
  k_out<<<dim3(4, 1563), 256, 0, stream>>>(epack, apack, info, out);
}

// Round 5
// 484.946 us; speedup vs baseline: 1.7053x; 1.0808x over previous
//
#include <hip/hip_runtime.h>
#include <math.h>

#define BATCH 512
#define SEQL  100
#define DIM   128
#define NITEMS 100000
#define NEGV  -1000000000.0f

// ---- workspace layout (float offsets) ----
// 0 .. 32768: wpack2 (W_in/W_out bf16 hi/lo B-frags, 65536 halves)
#define OFF_WREADT 131072    // 384x128  [j*128+i]
#define OFF_XIN    296960    // 51200x128 (head reused for apack after k_gru)
#define OFF_HOUT   6850560   // 51200x128 (later holds H; dead after k_attn)
#define OFF_EPACK_F (OFF_XIN + 131072)  // 12804096 floats; overlaps XIN tail + HOUT,
                                        // written by k_epack AFTER k_attn only.
// ---- int offsets (in ints from ws base) ----
#define OFF_NODES_I 13404160 // 512x100 tokens (padded with 0)
#define OFF_SRC_I   13455360 // 512x99
#define OFF_DST_I   13506048 // 512x99
#define OFF_INFO_I  13556736 // 512x4: ecnt, li, flag(cnt>=2), n_nodes
// packed GRU weights (bf16 hi/lo MFMA fragments), float offset
#define OFF_WPACK_F 13558784 // 196608 halves = 98304 floats

typedef __attribute__((ext_vector_type(8))) short bf16x8;
typedef __attribute__((ext_vector_type(4))) short s16x4;
typedef __attribute__((ext_vector_type(4))) float f32x4;

__device__ __forceinline__ unsigned short bf16_rne(float x) {
  unsigned int u = __float_as_uint(x);
  unsigned int r = u + 0x7FFFu + ((u >> 16) & 1u);
  return (unsigned short)(r >> 16);
}
__device__ __forceinline__ float bf16_to_f(unsigned short h) {
  return __uint_as_float(((unsigned int)h) << 16);
}

// ------------------------------------------------------------------
// K0 k_prep (r2-verified): wpack = w_ih/w_hh frags; wpack2 = W_in/W_out frags;
// WreadT.  frag rule: lane(quad,n) holds W[tile*16+n][chunk*32+quad*8+j]
__global__ void k_prep(const float* __restrict__ w_ih, const float* __restrict__ w_hh,
                       const float* __restrict__ W_in, const float* __restrict__ W_out,
                       const float* __restrict__ W_read, float* __restrict__ ws,
                       unsigned short* __restrict__ wpack) {
  int idx = blockIdx.x * 256 + threadIdx.x;
  if (idx < 98304) {
    int mat = idx / 49152, rem = idx % 49152;
    int n = rem / 128, k = rem % 128;
    float v = (mat ? w_hh : w_ih)[rem];          // (384,128) row-major
    unsigned short hi = bf16_rne(v);
    unsigned short lo = bf16_rne(v - bf16_to_f(hi));
    int nt = n >> 4, nn = n & 15, c = k >> 5, quad = (k >> 3) & 3, j = k & 7;
    int lane = quad * 16 + nn;
    size_t base = ((size_t)((mat * 24 + nt) * 4 + c)) * 1024 + (size_t)lane * 8 + j;
    wpack[base] = hi;
    wpack[base + 512] = lo;
  }
  if (idx < 49152) {
    int i = idx / 384, jj = idx % 384;           // W_read is (128,384) row-major
    ws[OFF_WREADT + jj * 128 + i] = W_read[idx];
  }
  if (idx < 32768) {                             // W_in/W_out (128,128) -> wpack2
    int mat = idx >> 14, rem = idx & 16383;
    int n = rem >> 7, k = rem & 127;
    float v = (mat ? W_out : W_in)[rem];
    unsigned short hi = bf16_rne(v);
    unsigned short lo = bf16_rne(v - bf16_to_f(hi));
    int nt = n >> 4, nn = n & 15, c = k >> 5, quad = (k >> 3) & 3, j = k & 7;
    int lane = quad * 16 + nn;
    size_t base = ((size_t)((mat * 8 + nt) * 4 + c)) * 1024 + (size_t)lane * 8 + j;
    unsigned short* wpack2 = (unsigned short*)ws;
    wpack2[base] = hi;
    wpack2[base + 512] = lo;
  }
}

// ------------------------------------------------------------------
// K1 k_build (r4-verified parallel version): dedup/edges.  grid=512, block=128.
__global__ void k_build(const int* __restrict__ x, int* __restrict__ nodes,
                        int* __restrict__ esrc, int* __restrict__ edst,
                        int* __restrict__ info) {
  int b = blockIdx.x, tid = threadIdx.x;
  __shared__ int sseq[SEQL];
  __shared__ unsigned char sisf[SEQL];
  __shared__ int srank[SEQL];
  __shared__ int scinv[SEQL];
  __shared__ int snodes[SEQL];
  __shared__ int s_nn, s_cnt;
  if (tid < SEQL) { sseq[tid] = x[b * SEQL + tid]; snodes[tid] = 0; }
  __syncthreads();
  int t = (tid < SEQL) ? sseq[tid] : 0;
  bool valid = (tid < SEQL) && (t != 0);
  int f = tid;
  if (valid) {
    for (int j = 0; j < tid; ++j) if (sseq[j] == t) { f = j; break; }
  }
  int isf = (valid && f == tid) ? 1 : 0;
  if (tid < SEQL) sisf[tid] = (unsigned char)isf;
  __syncthreads();
  int rank = 0, pos = 0;
  if (tid < SEQL) {
    for (int i = 0; i < tid; ++i) {
      rank += sisf[i];
      pos += (sseq[i] != 0) ? 1 : 0;
    }
    srank[tid] = rank;
    if (tid == SEQL - 1) { s_nn = rank + isf; s_cnt = pos + (valid ? 1 : 0); }
  }
  __syncthreads();
  if (valid) scinv[pos] = srank[f];
  if (isf) snodes[rank] = t;
  __syncthreads();
  int cnt = s_cnt;
  int ec = (cnt >= 2) ? cnt - 1 : 0;
  if (tid < ec) {
    esrc[b * 99 + tid] = scinv[tid];
    edst[b * 99 + tid] = scinv[tid + 1];
  }
  if (tid == 0) {
    info[b * 4 + 0] = ec;
    info[b * 4 + 1] = (cnt >= 1) ? scinv[cnt - 1] : 0;
    info[b * 4 + 2] = (cnt >= 2) ? 1 : 0;
    info[b * 4 + 3] = s_nn;
  }
  if (tid < SEQL) nodes[b * SEQL + tid] = snodes[tid];
}

// ------------------------------------------------------------------
// K2 k_gemm_inout (r2-verified): XIN = gather(emb) @ W_inT ; HOUT = @ W_outT
// split-bf16 MFMA.  grid=1600 (32 rows), block=128.
#define GPAD 136
__global__ __launch_bounds__(128) void k_gemm_inout(
    const float* __restrict__ emb, const unsigned short* __restrict__ wpack2,
    const int* __restrict__ nodes, float* __restrict__ xin, float* __restrict__ hout) {
  __shared__ unsigned short Hhi[32 * GPAD];
  __shared__ unsigned short Hlo[32 * GPAD];
  int tid = threadIdx.x;
  int rowbase = blockIdx.x * 32;
  const float4* emb4 = (const float4*)emb;
  for (int e = tid; e < 32 * 32; e += 128) {
    int r = e >> 5, c4 = e & 31;
    int tok = nodes[rowbase + r];
    float4 hv = emb4[(size_t)tok * 32 + c4];
    int base = r * GPAD + c4 * 4;
    float hs[4] = {hv.x, hv.y, hv.z, hv.w};
    #pragma unroll
    for (int q = 0; q < 4; ++q) {
      unsigned short hh = bf16_rne(hs[q]);
      Hhi[base + q] = hh;
      Hlo[base + q] = bf16_rne(hs[q] - bf16_to_f(hh));
    }
  }
  __syncthreads();
  int wave = tid >> 6, lane = tid & 63;
  int quad = lane >> 4, nIdx = lane & 15;
  int mrow = wave * 16 + nIdx;
  bf16x8 aH[4], aL[4];
  #pragma unroll
  for (int c = 0; c < 4; ++c) {
    int off = mrow * GPAD + c * 32 + quad * 8;
    aH[c] = *(const bf16x8*)&Hhi[off];
    aL[c] = *(const bf16x8*)&Hlo[off];
  }
  for (int t = 0; t < 8; ++t) {
    f32x4 accI = (f32x4){0.f, 0.f, 0.f, 0.f};
    f32x4 accO = (f32x4){0.f, 0.f, 0.f, 0.f};
    #pragma unroll
    for (int c = 0; c < 4; ++c) {
      size_t bi = ((size_t)((0 * 8 + t) * 4 + c)) * 1024 + (size_t)lane * 8;
      size_t bo = ((size_t)((1 * 8 + t) * 4 + c)) * 1024 + (size_t)lane * 8;
      bf16x8 BiH = *(const bf16x8*)&wpack2[bi];
      bf16x8 BiL = *(const bf16x8*)&wpack2[bi + 512];
      bf16x8 BoH = *(const bf16x8*)&wpack2[bo];
      bf16x8 BoL = *(const bf16x8*)&wpack2[bo + 512];
      accI = __builtin_amdgcn_mfma_f32_16x16x32_bf16(aH[c], BiH, accI, 0, 0, 0);
      accO = __builtin_amdgcn_mfma_f32_16x16x32_bf16(aH[c], BoH, accO, 0, 0, 0);
      accI = __builtin_amdgcn_mfma_f32_16x16x32_bf16(aL[c], BiH, accI, 0, 0, 0);
      accO = __builtin_amdgcn_mfma_f32_16x16x32_bf16(aL[c], BoH, accO, 0, 0, 0);
      accI = __builtin_amdgcn_mfma_f32_16x16x32_bf16(aH[c], BiL, accI, 0, 0, 0);
      accO = __builtin_amdgcn_mfma_f32_16x16x32_bf16(aH[c], BoL, accO, 0, 0, 0);
    }
    int j = t * 16 + nIdx;
    #pragma unroll
    for (int i = 0; i < 4; ++i) {
      size_t row = (size_t)(rowbase + wave * 16 + quad * 4 + i);
      xin[row * 128 + j]  = accI[i];
      hout[row * 128 + j] = accO[i];
    }
  }
}

// ------------------------------------------------------------------
// K3 k_scatter v2: parallel (edge x dim) with LDS fp32 atomics (pattern
// verified as k_agg in r4); deg computed in-kernel.  grid=512, block=256.
__global__ __launch_bounds__(256) void k_scatter(
    const float* __restrict__ hout, float* __restrict__ xin,
    const int* __restrict__ esrc, const int* __restrict__ edst,
    const int* __restrict__ info) {
  __shared__ float agg[SEQL * DIM];
  __shared__ float sdeg[SEQL];
  int b = blockIdx.x, tid = threadIdx.x;
  float4* a4 = (float4*)agg;
  for (int e = tid; e < SEQL * 32; e += 256) a4[e] = (float4){0.f, 0.f, 0.f, 0.f};
  if (tid < SEQL) sdeg[tid] = 0.f;
  __syncthreads();
  int ec = info[b * 4 + 0];
  if (tid < ec) atomicAdd(&sdeg[edst[b * 99 + tid]], 1.f);
  for (int idx = tid; idx < ec * DIM; idx += 256) {
    int e = idx >> 7, k = idx & 127;
    int s = esrc[b * 99 + e], dn = edst[b * 99 + e];
    atomicAdd(&agg[dn * DIM + k], hout[((size_t)(b * SEQL + s)) * DIM + k]);
  }
  __syncthreads();
  for (int idx = tid; idx < SEQL * DIM; idx += 256) {
    int n = idx >> 7;
    size_t g = ((size_t)b * SEQL) * DIM + idx;
    xin[g] += agg[idx] * (1.f / fmaxf(sdeg[n], 1.f));
  }
}

// ------------------------------------------------------------------
// K4 k_gru (r2-verified): split-bf16 MFMA GRU.  grid=1600 (32 rows), block=128.
__global__ __launch_bounds__(128) void k_gru(
    const float* __restrict__ emb, const int* __restrict__ nodes,
    const unsigned short* __restrict__ wpack, const float* __restrict__ xin,
    const float* __restrict__ b_ih, const float* __restrict__ b_hh,
    const int* __restrict__ info, float* __restrict__ Hbuf) {
  __shared__ unsigned short Xhi[32 * GPAD];
  __shared__ unsigned short Xlo[32 * GPAD];
  __shared__ unsigned short Hhi[32 * GPAD];
  __shared__ unsigned short Hlo[32 * GPAD];
  int tid = threadIdx.x;
  int rowbase = blockIdx.x * 32;
  const float4* emb4 = (const float4*)emb;
  const float4* xin4 = (const float4*)xin;
  for (int e = tid; e < 32 * 32; e += 128) {
    int r = e >> 5, c4 = e & 31;
    int row = rowbase + r;
    float4 xv = xin4[(size_t)row * 32 + c4];
    int tok = nodes[row];
    float4 hv = emb4[(size_t)tok * 32 + c4];
    int base = r * GPAD + c4 * 4;
    float xs[4] = {xv.x, xv.y, xv.z, xv.w};
    float hs[4] = {hv.x, hv.y, hv.z, hv.w};
    #pragma unroll
    for (int q = 0; q < 4; ++q) {
      unsigned short xh = bf16_rne(xs[q]);
      Xhi[base + q] = xh; Xlo[base + q] = bf16_rne(xs[q] - bf16_to_f(xh));
      unsigned short hh = bf16_rne(hs[q]);
      Hhi[base + q] = hh; Hlo[base + q] = bf16_rne(hs[q] - bf16_to_f(hh));
    }
  }
  __syncthreads();
  int wave = tid >> 6, lane = tid & 63;
  int quad = lane >> 4, nIdx = lane & 15;
  int mrow = wave * 16 + nIdx;
  bf16x8 aXh[4], aXl[4], aHh[4], aHl[4];
  #pragma unroll
  for (int c = 0; c < 4; ++c) {
    int off = mrow * GPAD + c * 32 + quad * 8;
    aXh[c] = *(const bf16x8*)&Xhi[off];
    aXl[c] = *(const bf16x8*)&Xlo[off];
    aHh[c] = *(const bf16x8*)&Hhi[off];
    aHl[c] = *(const bf16x8*)&Hlo[off];
  }
  int grows[4]; int zm[4];
  #pragma unroll
  for (int i = 0; i < 4; ++i) {
    int grow = rowbase + wave * 16 + quad * 4 + i;
    grows[i] = grow;
    int bs = grow / SEQL;
    int n = grow - bs * SEQL;
    zm[i] = (n < info[bs * 4 + 3]) ? 1 : 0;
  }

  for (int t = 0; t < 8; ++t) {
    f32x4 acc[3][2];
    #pragma unroll
    for (int g = 0; g < 3; ++g)
      #pragma unroll
      for (int m = 0; m < 2; ++m) acc[g][m] = (f32x4){0.f, 0.f, 0.f, 0.f};

    for (int c = 0; c < 4; ++c) {
      bf16x8 Bh[3][2], Bl[3][2];
      #pragma unroll
      for (int g = 0; g < 3; ++g) {
        int nt = g * 8 + t;
        #pragma unroll
        for (int m = 0; m < 2; ++m) {
          size_t bidx = (size_t)((m * 24 + nt) * 4 + c) * 1024 + (size_t)lane * 8;
          Bh[g][m] = *(const bf16x8*)&wpack[bidx];
          Bl[g][m] = *(const bf16x8*)&wpack[bidx + 512];
        }
      }
      #pragma unroll
      for (int g = 0; g < 3; ++g) {
        acc[g][0] = __builtin_amdgcn_mfma_f32_16x16x32_bf16(aXh[c], Bh[g][0], acc[g][0], 0, 0, 0);
        acc[g][1] = __builtin_amdgcn_mfma_f32_16x16x32_bf16(aHh[c], Bh[g][1], acc[g][1], 0, 0, 0);
      }
      #pragma unroll
      for (int g = 0; g < 3; ++g) {
        acc[g][0] = __builtin_amdgcn_mfma_f32_16x16x32_bf16(aXh[c], Bl[g][0], acc[g][0], 0, 0, 0);
        acc[g][1] = __builtin_amdgcn_mfma_f32_16x16x32_bf16(aHh[c], Bl[g][1], acc[g][1], 0, 0, 0);
      }
      #pragma unroll
      for (int g = 0; g < 3; ++g) {
        acc[g][0] = __builtin_amdgcn_mfma_f32_16x16x32_bf16(aXl[c], Bh[g][0], acc[g][0], 0, 0, 0);
        acc[g][1] = __builtin_amdgcn_mfma_f32_16x16x32_bf16(aHl[c], Bh[g][1], acc[g][1], 0, 0, 0);
      }
    }
    int j = t * 16 + nIdx;
    float biR = b_ih[j],       bhR = b_hh[j];
    float biZ = b_ih[128 + j], bhZ = b_hh[128 + j];
    float biN = b_ih[256 + j], bhN = b_hh[256 + j];
    #pragma unroll
    for (int i = 0; i < 4; ++i) {
      float gr = acc[0][0][i] + biR + acc[0][1][i] + bhR;
      float gz = acc[1][0][i] + biZ + acc[1][1][i] + bhZ;
      float r = 1.f / (1.f + expf(-gr));
      float z = 1.f / (1.f + expf(-gz));
      float nct = tanhf(acc[2][0][i] + biN + r * (acc[2][1][i] + bhN));
      int lrow = wave * 16 + quad * 4 + i;
      float h0 = bf16_to_f(Hhi[lrow * GPAD + j]) + bf16_to_f(Hlo[lrow * GPAD + j]);
      float h = (1.f - z) * nct + z * h0;
      if (!zm[i]) h = 0.f;
      Hbuf[(size_t)grows[i] * 128 + j] = h;
    }
  }
}

// ------------------------------------------------------------------
// K5 k_attn (r4-verified): attention + h_read + apack fold.  grid=512, block=128
#define HLS 129
__global__ void k_attn(const float* __restrict__ Hbuf, const float* __restrict__ WrT,
                       const float* __restrict__ b_read, const int* __restrict__ info,
                       unsigned short* __restrict__ apack) {
  int b = blockIdx.x, tid = threadIdx.x;
  __shared__ float Hl[SEQL * HLS];
  __shared__ float sc[128];
  __shared__ float hl[128];
  __shared__ float att[SEQL];
  __shared__ float loc[128];
  __shared__ float redm[2], reds[2];
  int nn = info[b * 4 + 3], li = info[b * 4 + 1];
  for (int e = tid; e < SEQL * 128; e += 128) {
    int r = e >> 7, k = e & 127;
    Hl[r * HLS + k] = Hbuf[((size_t)(b * SEQL + r)) * DIM + k];
  }
  __syncthreads();
  hl[tid] = Hl[li * HLS + tid];
  __syncthreads();
  float scr = NEGV;
  if (tid < nn) {
    float s = 0.f;
    for (int k = 0; k < 128; ++k) s += Hl[tid * HLS + k] * hl[k];
    scr = s;
  }
  sc[tid] = scr;
  __syncthreads();
  float m = sc[tid];
  #pragma unroll
  for (int o = 32; o >= 1; o >>= 1) m = fmaxf(m, __shfl_xor(m, o, 64));
  if ((tid & 63) == 0) redm[tid >> 6] = m;
  __syncthreads();
  m = fmaxf(redm[0], redm[1]);
  float e = (tid < SEQL) ? expf(sc[tid] - m) : 0.f;
  float s = e;
  #pragma unroll
  for (int o = 32; o >= 1; o >>= 1) s += __shfl_xor(s, o, 64);
  if ((tid & 63) == 0) reds[tid >> 6] = s;
  __syncthreads();
  float inv = 1.f / (reds[0] + reds[1]);
  if (tid < SEQL) att[tid] = e * inv;
  __syncthreads();
  float lv = 0.f;
  for (int n = 0; n < SEQL; ++n) lv = fmaf(att[n], Hl[n * HLS + tid], lv);
  loc[tid] = lv;
  __syncthreads();
  float acc = b_read[tid];
  for (int j = 0; j < 128; ++j) acc = fmaf(WrT[j * 128 + tid], hl[j], acc);
  for (int j = 0; j < 128; ++j) acc = fmaf(WrT[(128 + j) * 128 + tid], loc[j], acc);
  float hr = tanhf(acc);
  int mt = b >> 4, rr = b & 15;
  int kc = tid >> 5, q2 = (tid >> 3) & 3, j2 = tid & 7;
  unsigned short hi = bf16_rne(hr);
  unsigned short lo = bf16_rne(hr - bf16_to_f(hi));
  size_t base = ((size_t)(mt * 4 + kc) * 2) * 512 + (size_t)(q2 * 16 + rr) * 8 + j2;
  apack[base] = hi;
  apack[base + 512] = lo;
}

// ------------------------------------------------------------------
// K6 k_epack (r2-verified): emb -> bf16 hi/lo A-frags (zero-pad to 100032).
__global__ __launch_bounds__(256) void k_epack(
    const float* __restrict__ emb, unsigned short* __restrict__ epack) {
  int idx = blockIdx.x * 256 + threadIdx.x;
  int lane = idx & 63;
  int kc = (idx >> 6) & 3;
  int it = idx >> 8;
  int quad = lane >> 4, rr = lane & 15;
  int row = it * 16 + rr;
  int kbase = kc * 32 + quad * 8;
  float4 v0 = {0.f, 0.f, 0.f, 0.f}, v1 = {0.f, 0.f, 0.f, 0.f};
  if (row < NITEMS) {
    const float4* p = (const float4*)(emb + (size_t)row * 128 + kbase);
    v0 = p[0]; v1 = p[1];
  }
  float vs[8] = {v0.x, v0.y, v0.z, v0.w, v1.x, v1.y, v1.z, v1.w};
  bf16x8 hi, lo;
  #pragma unroll
  for (int j = 0; j < 8; ++j) {
    unsigned short h = bf16_rne(vs[j]);
    hi[j] = (short)h;
    lo[j] = (short)bf16_rne(vs[j] - bf16_to_f(h));
  }
  size_t base = ((size_t)(it * 4 + kc) * 2) * 512 + (size_t)lane * 8;
  *(bf16x8*)&epack[base] = hi;
  *(bf16x8*)&epack[base + 512] = lo;
}

// ------------------------------------------------------------------
// K7 k_out (r2-verified): out = h_read @ emb^T, operand-swapped (C[item][b]).
// Pure-register.  grid (4, 1563), block 256 = 4 waves.
__global__ __launch_bounds__(256) void k_out(
    const unsigned short* __restrict__ epack, const unsigned short* __restrict__ apack,
    const int* __restrict__ info, float* __restrict__ out) {
  int tid = threadIdx.x;
  int wave = tid >> 6, lane = tid & 63;
  int quad = lane >> 4, nIdx = lane & 15;
  int b0   = blockIdx.x * 128;
  int itt0 = blockIdx.y * 4;
  int btg0 = blockIdx.x * 8 + wave * 2;

  bf16x8 bh[2][4], bl[2][4];
  #pragma unroll
  for (int m2 = 0; m2 < 2; ++m2)
    #pragma unroll
    for (int kc = 0; kc < 4; ++kc) {
      size_t base = ((size_t)((btg0 + m2) * 4 + kc) * 2) * 512 + (size_t)lane * 8;
      bh[m2][kc] = *(const bf16x8*)&apack[base];
      bl[m2][kc] = *(const bf16x8*)&apack[base + 512];
    }

  f32x4 acc[4][2];
  #pragma unroll
  for (int it = 0; it < 4; ++it)
    #pragma unroll
    for (int m2 = 0; m2 < 2; ++m2) acc[it][m2] = (f32x4){0.f, 0.f, 0.f, 0.f};

  #pragma unroll
  for (int it = 0; it < 4; ++it) {
    #pragma unroll
    for (int kc = 0; kc < 4; ++kc) {
      size_t abase = ((size_t)((itt0 + it) * 4 + kc) * 2) * 512 + (size_t)lane * 8;
      bf16x8 Ah = *(const bf16x8*)&epack[abase];
      bf16x8 Al = *(const bf16x8*)&epack[abase + 512];
      acc[it][0] = __builtin_amdgcn_mfma_f32_16x16x32_bf16(Ah, bh[0][kc], acc[it][0], 0, 0, 0);
      acc[it][1] = __builtin_amdgcn_mfma_f32_16x16x32_bf16(Ah, bh[1][kc], acc[it][1], 0, 0, 0);
      acc[it][0] = __builtin_amdgcn_mfma_f32_16x16x32_bf16(Al, bh[0][kc], acc[it][0], 0, 0, 0);
      acc[it][1] = __builtin_amdgcn_mfma_f32_16x16x32_bf16(Al, bh[1][kc], acc[it][1], 0, 0, 0);
      acc[it][0] = __builtin_amdgcn_mfma_f32_16x16x32_bf16(Ah, bl[0][kc], acc[it][0], 0, 0, 0);
      acc[it][1] = __builtin_amdgcn_mfma_f32_16x16x32_bf16(Ah, bl[1][kc], acc[it][1], 0, 0, 0);
    }
  }

  #pragma unroll
  for (int m2 = 0; m2 < 2; ++m2) {
    int b = b0 + (wave * 2 + m2) * 16 + nIdx;
    int flag = info[b * 4 + 2];
    #pragma unroll
    for (int it = 0; it < 4; ++it) {
      int ib = (itt0 + it) * 16 + quad * 4;
      if (ib < NITEMS) {
        float4 v;
        if (flag) {
          v.x = acc[it][m2][0]; v.y = acc[it][m2][1];
          v.z = acc[it][m2][2]; v.w = acc[it][m2][3];
        } else {
          v.x = (ib == 0) ? 0.f : NEGV; v.y = NEGV; v.z = NEGV; v.w = NEGV;
        }
        *(float4*)&out[(size_t)b * NITEMS + ib] = v;
      }
    }
  }
}

// ------------------------------------------------------------------
extern "C" void kernel_launch(void* const* d_in, const int* in_sizes, int n_in,
                              void* d_out, int out_size, void* d_ws, size_t ws_size,
                              hipStream_t stream) {
  const int*   x      = (const int*)d_in[0];
  const float* emb    = (const float*)d_in[2];
  const float* W_in   = (const float*)d_in[3];
  const float* W_out  = (const float*)d_in[4];
  const float* w_ih   = (const float*)d_in[5];
  const float* w_hh   = (const float*)d_in[6];
  const float* b_ih   = (const float*)d_in[7];
  const float* b_hh   = (const float*)d_in[8];
  const float* W_read = (const float*)d_in[9];
  const float* b_read = (const float*)d_in[10];
  float* ws  = (float*)d_ws;
  int*   wsi = (int*)d_ws;
  unsigned short* wpack  = (unsigned short*)(ws + OFF_WPACK_F);
  unsigned short* wpack2 = (unsigned short*)ws;
  unsigned short* apack  = (unsigned short*)(ws + OFF_XIN);      // xin dead after k_gru
  unsigned short* epack  = (unsigned short*)(ws + OFF_EPACK_F);  // xin tail+hout dead after k_attn
  float* out = (float*)d_out;

  k_prep<<<384, 256, 0, stream>>>(w_ih, w_hh, W_in, W_out, W_read, ws, wpack);
  k_build<<<BATCH, 128, 0, stream>>>(x, wsi + OFF_NODES_I,
                                     wsi + OFF_SRC_I, wsi + OFF_DST_I, wsi + OFF_INFO_I);
  k_gemm_inout<<<1600, 128, 0, stream>>>(emb, wpack2, wsi + OFF_NODES_I,
                                         ws + OFF_XIN, ws + OFF_HOUT);
  k_scatter<<<BATCH, 256, 0, stream>>>(ws + OFF_HOUT, ws + OFF_XIN,
                                       wsi + OFF_SRC_I, wsi + OFF_DST_I, wsi + OFF_INFO_I);
  k_gru<<<1600, 128, 0, stream>>>(emb, wsi + OFF_NODES_I, wpack, ws + OFF_XIN,
                                  b_ih, b_hh, wsi + OFF_INFO_I, ws + OFF_HOUT);
  k_attn<<<BATCH, 128, 0, stream>>>(ws + OFF_HOUT, ws + OFF_WREADT, b_read,
                                    wsi + OFF_INFO_I, apack);
  k_epack<<<6252, 256, 0, stream>>>(emb, epack);
  k_out<<<dim3(4, 1563), 256, 0, stream>>>(epack, apack, wsi + OFF_INFO_I, out);
}